// Round 1
// 305.094 us; speedup vs baseline: 1.0301x; 1.0301x over previous
//
#include <hip/hip_runtime.h>
#include <math.h>

#define B_   2
#define N_   4096
#define S_   48
#define NPL  32
#define NRAYS (B_*N_)          // 8192
#define NPTS  (NRAYS*S_)       // 393216
#define DELTA_ (2.0f/47.0f)

#define ST_ENT   4356                   // 66*66 single-texel entries per plane (8B each)
#define ST_TOTAL (64*ST_ENT)            // 278784

// ---- workspace layout (float offsets) ----
#define OFF_POSES  0                    // 384
#define OFF_MINMAX 384                  // 2 floats (gmin, gmax)
#define OFF_W1E    512                  // 64*256 bf16
#define OFF_W2E    8704                 // 48*64 bf16
#define OFF_B2E    10240                // 48 floats
#define OFF_ST     16384                // single-texel planes: ST_TOTAL uint2 -> ends 573952
#define OFF_PTS    573952               // float4 per point: NPTS*4 -> ends 2146816
#define OFF_DC     2146816              // depths_c [NPTS]
#define OFF_DF     2540032
#define OFF_SC     2933248
#define OFF_SF     3326464
#define OFF_CC     3719680              // colors_c bf16 [NPTS*32] -> ends 10011136
#define OFF_CF     10011136             // colors_f bf16 -> ends 16302592

typedef __attribute__((ext_vector_type(8))) short short8;
typedef __attribute__((ext_vector_type(4))) float f32x4;

__device__ __forceinline__ float softplus_f(float x) {
    return fmaxf(x, 0.f) + __logf(1.f + __expf(-fabsf(x)));
}
__device__ __forceinline__ float sigmoid_f(float x) {
    return __builtin_amdgcn_rcpf(1.f + __expf(-x));
}
__device__ __forceinline__ unsigned short bf16rne(float x) {
    unsigned u = __float_as_uint(x);
    u += 0x7FFFu + ((u >> 16) & 1u);
    return (unsigned short)(u >> 16);
}
__device__ __forceinline__ unsigned bf16pk(float lo, float hi) {
    return (unsigned)bf16rne(lo) | ((unsigned)bf16rne(hi) << 16);
}
__device__ __forceinline__ float bf2f(unsigned short v) {
    return __uint_as_float(((unsigned)v) << 16);
}
__device__ __forceinline__ float bflo(unsigned u) { return __uint_as_float(u << 16); }
__device__ __forceinline__ float bfhi(unsigned u) { return __uint_as_float(u & 0xffff0000u); }

__device__ void mul3(const double* a, const double* b, double* o) {
    for (int i = 0; i < 3; i++)
        for (int j = 0; j < 3; j++) {
            double s = 0.0;
            for (int k = 0; k < 3; k++) s += a[i*3+k]*b[k*3+j];
            o[i*3+j] = s;
        }
}

// ---- kernel 0: poses (double math), minmax reduction (no atomics), bf16 weights ----
__global__ void k_init(float* ws, const float* __restrict__ W1,
                       const float* __restrict__ W2, const float* __restrict__ b2,
                       const float* __restrict__ noise) {
    __shared__ float redmn[4], redmx[4];
    int t = threadIdx.x;
    if (t < 32) {
        double y = 1.0 - (t/31.0)*2.0;
        double rr = sqrt(fmax(1.0 - y*y, 0.0));
        double golden = M_PI*(sqrt(5.0) - 1.0);
        double th = golden*(double)t;
        double x = cos(th)*rr, z = sin(th)*rr;
        double phi   = atan2(z, sqrt(x*x + y*y));   // radians treated as degrees (faithful)
        double theta = atan2(y, x);
        double p  = phi/180.0*M_PI;
        double tt = theta/180.0*M_PI;
        double e  = 90.0/180.0*M_PI;
        double cp = cos(p), sp = sin(p), ct = cos(tt), st = sin(tt);
        double ce = cos(e), se = sin(e);
        double Ph[9] = {1,0,0,  0,cp,-sp,  0,sp,cp};
        double Th[9] = {ct,0,-st,  0,1,0,  st,0,ct};
        double Et[9] = {ce,se,0,  -se,ce,0,  0,0,1};
        double M3[9] = {-1,0,0,  0,0,1,  0,1,0};
        double A[9], Bm[9], R[9];
        mul3(Th, Ph, A);
        mul3(Et, A, Bm);
        mul3(M3, Bm, R);
        double radius = -1.307;
        double tv0 = radius*R[2], tv1 = radius*R[5], tv2 = radius*R[8];
        double Rf[9] = {-R[0],R[1],R[2], -R[3],R[4],R[5], -R[6],R[7],R[8]};
        float* P = ws + OFF_POSES + t*12;
        for (int j = 0; j < 3; j++) {
            double r0 = Rf[0*3+j], r1 = Rf[1*3+j], r2 = Rf[2*3+j];
            P[j*4+0] = (float)r0;
            P[j*4+1] = (float)r1;
            P[j*4+2] = (float)r2;
            P[j*4+3] = (float)(-(r0*tv0 + r1*tv1 + r2*tv2));
        }
    }
    unsigned short* w1e = (unsigned short*)(ws + OFF_W1E);
    for (int idx = t; idx < 64*256; idx += 256) {
        int n = idx >> 8, k = idx & 255;
        int p = k >> 3, f = k & 7;
        float v = 0.f;
        if (f < 3)      v = W1[(3*p+f)*64 + n];
        else if (f < 5) v = W1[(96 + 2*p + (f-3))*64 + n];
        w1e[idx] = bf16rne(v);
    }
    unsigned short* w2e = (unsigned short*)(ws + OFF_W2E);
    for (int idx = t; idx < 48*64; idx += 256) {
        int n = idx >> 6, k = idx & 63;
        float v = (n < 33) ? W2[k*33 + n] : 0.f;
        w2e[idx] = bf16rne(v);
    }
    for (int idx = t; idx < 48; idx += 256)
        ws[OFF_B2E + idx] = (idx < 33) ? b2[idx] : 0.f;

    // minmax over noise col 0 / col 47 (one block, no atomics)
    float mn = 1e30f, mx = -1e30f;
    for (int r = t; r < NRAYS; r += 256) {
        float n0  = noise[(size_t)r*48];
        float n47 = noise[(size_t)r*48 + 47];
        mn = fminf(mn, 0.5f + n0*DELTA_);
        mx = fmaxf(mx, 0.5f + 47.f*DELTA_ + n47*DELTA_);
    }
    for (int off = 32; off > 0; off >>= 1) {
        mn = fminf(mn, __shfl_down(mn, off));
        mx = fmaxf(mx, __shfl_down(mx, off));
    }
    if ((t & 63) == 0) { redmn[t >> 6] = mn; redmx[t >> 6] = mx; }
    __syncthreads();
    if (t == 0) {
        ws[OFF_MINMAX]     = fminf(fminf(redmn[0], redmn[1]), fminf(redmn[2], redmn[3]));
        ws[OFF_MINMAX + 1] = fmaxf(fmaxf(redmx[0], redmx[1]), fmaxf(redmx[2], redmx[3]));
    }
}

// ---- kernel 1: repack planes to guard-padded bf16 single texels (8B) ----
__global__ __launch_bounds__(256) void k_repack(const float* __restrict__ planes, uint2* __restrict__ st) {
    int idx = blockIdx.x*256 + threadIdx.x;
    if (idx >= ST_TOTAL) return;
    int bp = idx / ST_ENT;
    int rem = idx - bp*ST_ENT;
    int j = rem / 66, i = rem - j*66;
    unsigned ux = 0, uy = 0;
    if (j >= 1 && j <= 64 && i >= 1 && i <= 64) {
        int b = bp >> 5, p = bp & 31;
        const float* src = planes + (((size_t)b*96 + 3*p)*64 + (j-1))*64 + (i-1);
        ux = bf16pk(src[0], src[4096]);
        uy = (unsigned)bf16rne(src[8192]);
    }
    st[idx] = make_uint2(ux, uy);
}

// ---- kernel 1b: point prepass — position+depth once per point ----
__global__ __launch_bounds__(256) void k_pts(
    const float* __restrict__ noise, const float* __restrict__ ro,
    const float* __restrict__ rd, const float* __restrict__ dfin,
    float* __restrict__ dcout, float4* __restrict__ pts, int coarse)
{
    int pt = blockIdx.x*256 + threadIdx.x;
    if (pt >= NPTS) return;
    int ray = pt / S_;
    float depth;
    if (coarse) {
        int j = pt - ray*S_;
        depth = 0.5f + (float)j*DELTA_ + noise[pt]*DELTA_;
        dcout[pt] = depth;
    } else depth = dfin[pt];
    float px = fmaf(depth, rd[ray*3+0], ro[ray*3+0]);
    float py = fmaf(depth, rd[ray*3+1], ro[ray*3+1]);
    float pz = fmaf(depth, rd[ray*3+2], ro[ray*3+2]);
    pts[pt] = make_float4(px, py, pz, depth);
}

// ---- kernel 2: FUSED gather + MFMA MLP ----
// Key layout fact: for mfma_f32_16x16x32_bf16, lane (n,q) supplies A[row=n][k=q*8+j].
// K-group q of MFMA call s is exactly plane s*4+q with slots [f0,f1,f2,gx,gy,0,0,0].
// So lane (n,q) computes the projection+bilinear for planes {s*4+q} and points
// {t*16+n} itself — the result is born in the lane the MFMA needs. No feats buffer,
// no LDS redistribution. Texel table st (2.2 MB) is L2-resident -> ~200cy hits.
__global__ __launch_bounds__(256) void k_fused(
    const uint2* __restrict__ st, const float4* __restrict__ pts,
    const float* __restrict__ poses,
    const float* __restrict__ b1, const unsigned short* __restrict__ w1e,
    const unsigned short* __restrict__ w2e, const float* __restrict__ b2e,
    unsigned short* __restrict__ colors, float* __restrict__ dens)
{
    __shared__ __align__(16) unsigned short smem[4][4608];
    __shared__ __align__(16) float pl[384];
    int tid = threadIdx.x;
    int wv = tid >> 6, lane = tid & 63;
    int n = lane & 15, q = lane >> 4;
    int wlocal = blockIdx.x*256 + wv*64;
    int b = (wlocal >= NPTS/2) ? 1 : 0;      // 256-pt blocks never straddle the batch split

    for (int i = tid; i < 384; i += 256) pl[i] = poses[i];
    __syncthreads();

    // this lane's 4 point positions (shared across its 8 planes)
    float px[4], py[4], pz[4];
#pragma unroll
    for (int t = 0; t < 4; t++) {
        float4 pv = pts[wlocal + t*16 + n];
        px[t] = pv.x; py[t] = pv.y; pz[t] = pv.z;
    }

    f32x4 acc[4][4];
#pragma unroll
    for (int t = 0; t < 4; t++)
#pragma unroll
        for (int nt = 0; nt < 4; nt++) {
            float bv = b1[nt*16 + n];
            acc[t][nt] = (f32x4){bv, bv, bv, bv};
        }

    const uint2* stb = st + (size_t)(b*32)*ST_ENT;

#pragma unroll
    for (int s = 0; s < 8; s++) {
        short8 bf[4];
#pragma unroll
        for (int nt = 0; nt < 4; nt++)
            bf[nt] = *(const short8*)(w1e + (nt*16 + n)*256 + s*32 + q*8);
        int plane = s*4 + q;
        const f32x4* Pq = (const f32x4*)(pl + plane*12);
        f32x4 Pa = Pq[0], Pb = Pq[1], Pc = Pq[2];
        const uint2* stp = stb + (size_t)plane*ST_ENT;
        union { short8 s8; uint4 u; } av[4];
#pragma unroll
        for (int t = 0; t < 4; t++) {
            float c0 = fmaf(Pa.x,px[t], fmaf(Pa.y,py[t], fmaf(Pa.z,pz[t], Pa.w)));
            float c1 = fmaf(Pb.x,px[t], fmaf(Pb.y,py[t], fmaf(Pb.z,pz[t], Pb.w)));
            float c2 = fmaf(Pc.x,px[t], fmaf(Pc.y,py[t], fmaf(Pc.z,pz[t], Pc.w)));
            float rz = __builtin_amdgcn_rcpf(c2);
            float gx = fminf(fmaxf((1.0254f*c0 + 0.5f*c2)*rz, 0.f), 1.f)*2.f - 1.f;
            float gy = fminf(fmaxf((1.0254f*c1 + 0.5f*c2)*rz, 0.f), 1.f)*2.f - 1.f;
            float ixp = ((gx + 1.f)*64.f - 1.f)*0.5f + 1.f;
            float iyp = ((gy + 1.f)*64.f - 1.f)*0.5f + 1.f;
            float xf = floorf(ixp), yf = floorf(iyp);
            float wx = ixp - xf, wy = iyp - yf;
            int x0p = (int)xf, y0p = (int)yf;     // [0,64]
            const uint2* e = stp + y0p*66 + x0p;
            uint2 e00 = e[0], e01 = e[1], e10 = e[66], e11 = e[67];
            float wy0 = 1.f - wy, wy1 = wy;
            float w0x = 1.f - wx, w1x = wx;
            float tl0 = fmaf(wy0, bflo(e00.x), wy1*bflo(e10.x));
            float tl1 = fmaf(wy0, bfhi(e00.x), wy1*bfhi(e10.x));
            float tl2 = fmaf(wy0, bflo(e00.y), wy1*bflo(e10.y));
            float tr0 = fmaf(wy0, bflo(e01.x), wy1*bflo(e11.x));
            float tr1 = fmaf(wy0, bfhi(e01.x), wy1*bfhi(e11.x));
            float tr2 = fmaf(wy0, bflo(e01.y), wy1*bflo(e11.y));
            float f0 = fmaf(w0x, tl0, w1x*tr0);
            float f1 = fmaf(w0x, tl1, w1x*tr1);
            float f2 = fmaf(w0x, tl2, w1x*tr2);
            av[t].u.x = bf16pk(f0, f1);
            av[t].u.y = bf16pk(f2, gx);
            av[t].u.z = (unsigned)bf16rne(gy);
            av[t].u.w = 0u;
        }
#pragma unroll
        for (int t = 0; t < 4; t++)
#pragma unroll
            for (int nt = 0; nt < 4; nt++)
                acc[t][nt] = __builtin_amdgcn_mfma_f32_16x16x32_bf16(av[t].s8, bf[nt], acc[t][nt], 0, 0, 0);
    }

    unsigned short* ht = &smem[wv][0];
#pragma unroll
    for (int t = 0; t < 4; t++)
#pragma unroll
        for (int nt = 0; nt < 4; nt++)
#pragma unroll
            for (int r = 0; r < 4; r++) {
                float hv = softplus_f(acc[t][nt][r]);
                ht[(t*16 + q*4 + r)*72 + nt*16 + n] = bf16rne(hv);
            }
    short8 a2[4][2];
#pragma unroll
    for (int t = 0; t < 4; t++)
#pragma unroll
        for (int s2 = 0; s2 < 2; s2++)
            a2[t][s2] = *(const short8*)(ht + (t*16 + n)*72 + s2*32 + q*8);
    // no __syncthreads: aliasing is wave-local; DS pipe in-order per wave

    f32x4 acc2[4][3];
#pragma unroll
    for (int t = 0; t < 4; t++)
#pragma unroll
        for (int nt = 0; nt < 3; nt++) {
            float bv = b2e[nt*16 + n];
            acc2[t][nt] = (f32x4){bv, bv, bv, bv};
        }
    short8 b2f[3][2];
#pragma unroll
    for (int nt = 0; nt < 3; nt++)
#pragma unroll
        for (int s2 = 0; s2 < 2; s2++)
            b2f[nt][s2] = *(const short8*)(w2e + (nt*16 + n)*64 + s2*32 + q*8);
#pragma unroll
    for (int t = 0; t < 4; t++)
#pragma unroll
        for (int nt = 0; nt < 3; nt++)
#pragma unroll
            for (int s2 = 0; s2 < 2; s2++)
                acc2[t][nt] = __builtin_amdgcn_mfma_f32_16x16x32_bf16(a2[t][s2], b2f[nt][s2], acc2[t][nt], 0, 0, 0);

    float* ot = (float*)&smem[wv][0];
#pragma unroll
    for (int t = 0; t < 4; t++)
#pragma unroll
        for (int nt = 0; nt < 3; nt++) {
            int col = nt*16 + n;
#pragma unroll
            for (int r = 0; r < 4; r++) {
                float v = acc2[t][nt][r];
                int row = t*16 + q*4 + r;
                if (col == 0) ot[row*34 + 32] = v;
                else if (col <= 32) {
                    float sg = sigmoid_f(v);
                    ot[row*34 + (col-1)] = fmaf(sg, 1.002f, -0.001f);
                }
            }
        }
    unsigned* cgu = (unsigned*)(colors + (size_t)wlocal*32);
    for (int i = 0; i < 16; i++) {
        int ui = i*64 + lane;
        int pt = ui >> 4, ch = (ui & 15)*2;
        cgu[ui] = bf16pk(ot[pt*34 + ch], ot[pt*34 + ch + 1]);
    }
    dens[wlocal + lane] = ot[lane*34 + 32];
}

// ---- kernel 3: coarse march + pdf + importance samples (wave per ray) ----
__global__ __launch_bounds__(256) void k_imp(const float* __restrict__ u, float* ws) {
    __shared__ float zl[4][48];
    __shared__ float cdfl[4][46];
    int tid = threadIdx.x;
    int wv = tid >> 6, lane = tid & 63;
    int r = blockIdx.x*4 + wv;
    const float* z   = ws + OFF_DC + (size_t)r*48;
    const float* den = ws + OFF_SC + (size_t)r*48;
    float zv = 0.f, dv = 0.f;
    if (lane < 48) { zv = z[lane]; dv = den[lane]; zl[wv][lane] = zv; }
    float zn  = __shfl_down(zv, 1);
    float dnn = __shfl_down(dv, 1);
    float alpha = 0.f, f = 1.f;
    if (lane < 47) {
        float sp = softplus_f(0.5f*(dv + dnn) - 1.f);
        alpha = 1.f - __expf(-sp*(zn - zv));
        f = 1.f - alpha + 1e-10f;
    }
    float v = f;
    for (int off = 1; off < 64; off <<= 1) { float o = __shfl_up(v, off); if (lane >= off) v *= o; }
    float T = __shfl_up(v, 1); if (lane == 0) T = 1.f;
    float w = alpha*T;
    float wn1 = __shfl_down(w, 1), wn2 = __shfl_down(w, 2);
    float pw = 0.f;
    if (lane < 45) pw = 0.5f*(fmaxf(w, wn1) + fmaxf(wn1, wn2)) + 0.01f + 1e-5f;
    float s = pw;
    for (int off = 1; off < 64; off <<= 1) { float o = __shfl_up(s, off); if (lane >= off) s += o; }
    float csum = __shfl(s, 63);
    if (lane < 45) cdfl[wv][lane+1] = s/csum;
    if (lane == 63) cdfl[wv][0] = 0.f;
    __syncthreads();
    if (lane < 48) {
        float uu = u[(size_t)r*48 + lane];
        int lo = 0, hi = 46;
        while (lo < hi) { int mid = (lo+hi)>>1; if (uu >= cdfl[wv][mid]) lo = mid+1; else hi = mid; }
        int below = max(lo-1, 0), above = min(lo, 45);
        float cb = cdfl[wv][below], ca = cdfl[wv][above];
        float zb = zl[wv][below],   za = zl[wv][above];
        float dn2 = ca - cb; if (dn2 < 1e-5f) dn2 = 1.f;
        ws[OFF_DF + (size_t)r*48 + lane] = zb + (uu - cb)/dn2*(za - zb);
    }
}

// ---- kernel 5: fused sort + march + color accumulation (wave per ray) ----
__global__ __launch_bounds__(256) void k_final(float* __restrict__ out, const float* __restrict__ ws,
                                               const unsigned short* __restrict__ cC,
                                               const unsigned short* __restrict__ cF)
{
    __shared__ float kd[4][96];
    __shared__ float kden[4][96];
    __shared__ float sdl[4][96];
    __shared__ float sdenl[4][96];
    __shared__ int   sidxl[4][96];
    __shared__ float warr[4][96];
    __shared__ float earr[4][96];
    int tid = threadIdx.x;
    int wv = tid >> 6, lane = tid & 63;
    int r = blockIdx.x*4 + wv;
    const float* dc = ws + OFF_DC + (size_t)r*48;
    const float* df = ws + OFF_DF + (size_t)r*48;
    const float* sc = ws + OFF_SC + (size_t)r*48;
    const float* sf = ws + OFF_SF + (size_t)r*48;
    for (int i = lane; i < 96; i += 64) {
        float d, dn;
        if (i < 48) { d = dc[i]; dn = sc[i]; }
        else        { d = df[i-48]; dn = sf[i-48]; }
        kd[wv][i] = d; kden[wv][i] = dn;
    }
    __syncthreads();
    for (int i = lane; i < 96; i += 64) {
        float d = kd[wv][i];
        int rank = 0;
        for (int j = 0; j < 96; j++) {
            float dj = kd[wv][j];
            rank += (int)((dj < d) | ((dj == d) & (j < i)));
        }
        sdl[wv][rank] = d; sdenl[wv][rank] = kden[wv][i]; sidxl[wv][rank] = i;
    }
    __syncthreads();
    int i2 = 2*lane;
    float a0=0.f, f0=1.f, a1=0.f, f1=1.f, d0=0.f, d1=0.f, d2=0.f;
    if (i2 < 95) {
        d0 = sdl[wv][i2]; d1 = sdl[wv][i2+1];
        float sp = softplus_f(0.5f*(sdenl[wv][i2] + sdenl[wv][i2+1]) - 1.f);
        a0 = 1.f - __expf(-sp*(d1 - d0)); f0 = 1.f - a0 + 1e-10f;
    }
    if (i2+1 < 95) {
        d2 = sdl[wv][i2+2];
        float sp = softplus_f(0.5f*(sdenl[wv][i2+1] + sdenl[wv][i2+2]) - 1.f);
        a1 = 1.f - __expf(-sp*(d2 - d1)); f1 = 1.f - a1 + 1e-10f;
    }
    float p = f0*f1, v = p;
    for (int off = 1; off < 64; off <<= 1) { float o = __shfl_up(v, off); if (lane >= off) v *= o; }
    float excl = __shfl_up(v, 1); if (lane == 0) excl = 1.f;
    float w0 = a0*excl, w1 = a1*excl*f0;
    if (i2   < 96) warr[wv][i2]   = w0;
    if (i2+1 < 96) warr[wv][i2+1] = w1;
    float wsm = w0 + w1;
    float dsm = w0*0.5f*(d0+d1) + w1*0.5f*(d1+d2);
    for (int off = 32; off; off >>= 1) { wsm += __shfl_xor(wsm, off); dsm += __shfl_xor(dsm, off); }
    __syncthreads();
    for (int i = lane; i < 96; i += 64) {
        float wp = (i > 0)  ? warr[wv][i-1] : 0.f;
        float wc = (i < 95) ? warr[wv][i]   : 0.f;
        earr[wv][sidxl[wv][i]] = 0.5f*(wp + wc);
    }
    __syncthreads();
    int ch = lane & 31, half = lane >> 5;
    const unsigned short* cbase = (half ? cF : cC) + ((size_t)r*48)*32 + ch;
    const float* eb = &earr[wv][half*48];
    float a = 0.f;
    for (int jj = 0; jj < 48; jj++)
        a = fmaf(eb[jj], bf2f(cbase[(size_t)jj*32]), a);
    a += __shfl_xor(a, 32);
    if (lane < 32) out[(size_t)r*34 + lane] = 2.f*a - 1.f;
    if (lane == 0) {
        float gmn = ws[OFF_MINMAX];
        float gmx = ws[OFF_MINMAX + 1];
        float depth = dsm/wsm;
        if (depth != depth) depth = __builtin_inff();
        depth = fminf(fmaxf(depth, gmn), gmx);
        out[(size_t)r*34 + 32] = depth;
        out[(size_t)r*34 + 33] = wsm;
    }
}

extern "C" void kernel_launch(void* const* d_in, const int* in_sizes, int n_in,
                              void* d_out, int out_size, void* d_ws, size_t ws_size,
                              hipStream_t stream) {
    const float* planes = (const float*)d_in[0];
    const float* ro     = (const float*)d_in[1];
    const float* rd     = (const float*)d_in[2];
    const float* noise  = (const float*)d_in[3];
    const float* u      = (const float*)d_in[4];
    const float* W1     = (const float*)d_in[5];
    const float* b1     = (const float*)d_in[6];
    const float* W2     = (const float*)d_in[7];
    const float* b2     = (const float*)d_in[8];
    float* ws  = (float*)d_ws;
    float* out = (float*)d_out;
    const unsigned short* w1e = (const unsigned short*)(ws + OFF_W1E);
    const unsigned short* w2e = (const unsigned short*)(ws + OFF_W2E);
    uint2* st = (uint2*)(ws + OFF_ST);
    float4* pts = (float4*)(ws + OFF_PTS);
    unsigned short* cC = (unsigned short*)(ws + OFF_CC);
    unsigned short* cF = (unsigned short*)(ws + OFF_CF);

    hipLaunchKernelGGL(k_init,   dim3(1),    dim3(256), 0, stream, ws, W1, W2, b2, noise);
    hipLaunchKernelGGL(k_repack, dim3((ST_TOTAL + 255)/256), dim3(256), 0, stream, planes, st);
    hipLaunchKernelGGL(k_pts,    dim3(NPTS/256), dim3(256), 0, stream,
                       noise, ro, rd, (const float*)nullptr, ws + OFF_DC, pts, 1);
    hipLaunchKernelGGL(k_fused,  dim3(NPTS/256), dim3(256), 0, stream,
                       st, pts, ws + OFF_POSES, b1, w1e, w2e, ws + OFF_B2E, cC, ws + OFF_SC);
    hipLaunchKernelGGL(k_imp, dim3(NRAYS/4), dim3(256), 0, stream, u, ws);
    hipLaunchKernelGGL(k_pts, dim3(NPTS/256), dim3(256), 0, stream,
                       noise, ro, rd, ws + OFF_DF, ws + OFF_DC, pts, 0);
    hipLaunchKernelGGL(k_fused,  dim3(NPTS/256), dim3(256), 0, stream,
                       st, pts, ws + OFF_POSES, b1, w1e, w2e, ws + OFF_B2E, cF, ws + OFF_SF);
    hipLaunchKernelGGL(k_final, dim3(NRAYS/4), dim3(256), 0, stream, out, ws, cC, cF);
}

// Round 3
// 288.967 us; speedup vs baseline: 1.0875x; 1.0558x over previous
//
#include <hip/hip_runtime.h>
#include <math.h>

#define B_   2
#define N_   4096
#define S_   48
#define NPL  32
#define NRAYS (B_*N_)          // 8192
#define NPTS  (NRAYS*S_)       // 393216
#define DELTA_ (2.0f/47.0f)

// quad-texel table: entry (plane, y0, x0) = 2x2 bf16 texel stencil, 32B
#define QT_XS    66                     // x stride (x0 in [0,64], 1 pad col)
#define QT_YS    65                     // y0 in [0,64]
#define QT_PLANE (QT_YS*QT_XS)          // 4290 entries per plane
#define QT_TOTAL (64*QT_PLANE)          // 274560 entries (2 batches x 32 planes)
#define QT_BLOCKS ((QT_TOTAL + 255)/256)        // 1073
#define SETUP_GRID (1 + QT_BLOCKS + NPTS/256)   // 1 init + repack + coarse pts

// ---- workspace layout (float offsets) ----
#define OFF_POSES  0                    // 384
#define OFF_MINMAX 384                  // 2 floats (gmin, gmax)
#define OFF_W1E    512                  // 64*256 bf16 = 8192 floats
#define OFF_W2E    8704                 // 48*64 bf16
#define OFF_B2E    10240                // 48 floats
#define OFF_ST     16384                // quad table: QT_TOTAL*8 floats -> ends 2212864
#define OFF_PTS    2212864              // float4 per point: NPTS*4 -> ends 3785728
#define OFF_DC     3785728              // depths_c [NPTS]
#define OFF_DF     4178944
#define OFF_SC     4572160
#define OFF_SF     4965376
#define OFF_CC     5358592              // colors_c bf16 [NPTS*32] -> ends 11650048
#define OFF_CF     11650048             // colors_f bf16 -> ends 17941504

typedef __attribute__((ext_vector_type(8))) short short8;
typedef __attribute__((ext_vector_type(4))) float f32x4;

__device__ __forceinline__ float softplus_f(float x) {
    return fmaxf(x, 0.f) + __logf(1.f + __expf(-fabsf(x)));
}
__device__ __forceinline__ float sigmoid_f(float x) {
    return __builtin_amdgcn_rcpf(1.f + __expf(-x));
}
__device__ __forceinline__ unsigned short bf16rne(float x) {
    unsigned u = __float_as_uint(x);
    u += 0x7FFFu + ((u >> 16) & 1u);
    return (unsigned short)(u >> 16);
}
__device__ __forceinline__ unsigned bf16pk(float lo, float hi) {
    return (unsigned)bf16rne(lo) | ((unsigned)bf16rne(hi) << 16);
}
__device__ __forceinline__ float bf2f(unsigned short v) {
    return __uint_as_float(((unsigned)v) << 16);
}
__device__ __forceinline__ float bflo(unsigned u) { return __uint_as_float(u << 16); }
__device__ __forceinline__ float bfhi(unsigned u) { return __uint_as_float(u & 0xffff0000u); }

__device__ void mul3(const double* a, const double* b, double* o) {
    for (int i = 0; i < 3; i++)
        for (int j = 0; j < 3; j++) {
            double s = 0.0;
            for (int k = 0; k < 3; k++) s += a[i*3+k]*b[k*3+j];
            o[i*3+j] = s;
        }
}

// ---- kernel A: global depth minmax (1 block, no atomics, no sentinels) ----
__global__ __launch_bounds__(1024) void k_mm(const float* __restrict__ noise, float* ws) {
    __shared__ float smn[16], smx[16];
    int t = threadIdx.x;
    float mn = 1e30f, mx = -1e30f;
    for (int r = t; r < NRAYS; r += 1024) {
        float n0  = noise[(size_t)r*48];
        float n47 = noise[(size_t)r*48 + 47];
        mn = fminf(mn, 0.5f + n0*DELTA_);
        mx = fmaxf(mx, 0.5f + 47.f*DELTA_ + n47*DELTA_);
    }
    for (int off = 32; off > 0; off >>= 1) {
        mn = fminf(mn, __shfl_down(mn, off));
        mx = fmaxf(mx, __shfl_down(mx, off));
    }
    if ((t & 63) == 0) { smn[t >> 6] = mn; smx[t >> 6] = mx; }
    __syncthreads();
    if (t == 0) {
        for (int i = 1; i < 16; i++) { mn = fminf(mn, smn[i]); mx = fmaxf(mx, smx[i]); }
        ws[OFF_MINMAX]     = mn;
        ws[OFF_MINMAX + 1] = mx;
    }
}

// ---- kernel 0: setup — block 0: poses+weights; blocks [1,QT_BLOCKS]: quad repack;
// ---- remaining blocks: coarse point prepass ----
__global__ __launch_bounds__(256) void k_setup(
    float* ws, const float* __restrict__ W1,
    const float* __restrict__ W2, const float* __restrict__ b2,
    const float* __restrict__ planes, const float* __restrict__ noise,
    const float* __restrict__ ro, const float* __restrict__ rd)
{
    int bid = blockIdx.x;
    int t = threadIdx.x;
    if (bid == 0) {
        // poses (double math, faithful)
        if (t < 32) {
            double y = 1.0 - (t/31.0)*2.0;
            double rr = sqrt(fmax(1.0 - y*y, 0.0));
            double golden = M_PI*(sqrt(5.0) - 1.0);
            double th = golden*(double)t;
            double x = cos(th)*rr, z = sin(th)*rr;
            double phi   = atan2(z, sqrt(x*x + y*y));   // radians treated as degrees (faithful)
            double theta = atan2(y, x);
            double p  = phi/180.0*M_PI;
            double tt = theta/180.0*M_PI;
            double e  = 90.0/180.0*M_PI;
            double cp = cos(p), sp = sin(p), ct = cos(tt), st = sin(tt);
            double ce = cos(e), se = sin(e);
            double Ph[9] = {1,0,0,  0,cp,-sp,  0,sp,cp};
            double Th[9] = {ct,0,-st,  0,1,0,  st,0,ct};
            double Et[9] = {ce,se,0,  -se,ce,0,  0,0,1};
            double M3[9] = {-1,0,0,  0,0,1,  0,1,0};
            double A[9], Bm[9], R[9];
            mul3(Th, Ph, A);
            mul3(Et, A, Bm);
            mul3(M3, Bm, R);
            double radius = -1.307;
            double tv0 = radius*R[2], tv1 = radius*R[5], tv2 = radius*R[8];
            double Rf[9] = {-R[0],R[1],R[2], -R[3],R[4],R[5], -R[6],R[7],R[8]};
            float* P = ws + OFF_POSES + t*12;
            for (int j = 0; j < 3; j++) {
                double r0 = Rf[0*3+j], r1 = Rf[1*3+j], r2 = Rf[2*3+j];
                P[j*4+0] = (float)r0;
                P[j*4+1] = (float)r1;
                P[j*4+2] = (float)r2;
                P[j*4+3] = (float)(-(r0*tv0 + r1*tv1 + r2*tv2));
            }
        }
        unsigned short* w1e = (unsigned short*)(ws + OFF_W1E);
        for (int idx = t; idx < 64*256; idx += 256) {
            int n = idx >> 8, k = idx & 255;
            int p = k >> 3, f = k & 7;
            float v = 0.f;
            if (f < 3)      v = W1[(3*p+f)*64 + n];
            else if (f < 5) v = W1[(96 + 2*p + (f-3))*64 + n];
            w1e[idx] = bf16rne(v);
        }
        unsigned short* w2e = (unsigned short*)(ws + OFF_W2E);
        for (int idx = t; idx < 48*64; idx += 256) {
            int n = idx >> 6, k = idx & 63;
            float v = (n < 33) ? W2[k*33 + n] : 0.f;
            w2e[idx] = bf16rne(v);
        }
        for (int idx = t; idx < 48; idx += 256)
            ws[OFF_B2E + idx] = (idx < 33) ? b2[idx] : 0.f;
    } else if (bid <= QT_BLOCKS) {
        // quad-texel repack: each entry = 2x2 stencil (t00,t01,t10,t11) x 3ch bf16 in 32B
        int idx = (bid - 1)*256 + t;
        if (idx < QT_TOTAL) {
            int bp = idx / QT_PLANE;                 // global plane 0..63
            int rem = idx - bp*QT_PLANE;
            int y0 = rem / QT_XS, x0 = rem - y0*QT_XS;
            float c[4][3] = {{0.f,0.f,0.f},{0.f,0.f,0.f},{0.f,0.f,0.f},{0.f,0.f,0.f}};
            if (x0 <= 64) {
                int b = bp >> 5, p = bp & 31;
                const float* base = planes + ((size_t)b*96 + 3*p)*4096;
#pragma unroll
                for (int dy = 0; dy < 2; dy++) {
                    int jy = y0 - 1 + dy;
                    if (jy < 0 || jy > 63) continue;
#pragma unroll
                    for (int dx = 0; dx < 2; dx++) {
                        int jx = x0 - 1 + dx;
                        if (jx < 0 || jx > 63) continue;
                        const float* s = base + jy*64 + jx;
                        c[dy*2+dx][0] = s[0];
                        c[dy*2+dx][1] = s[4096];
                        c[dy*2+dx][2] = s[8192];
                    }
                }
            }
            uint4 qa, qb;
            qa.x = bf16pk(c[0][0], c[0][1]);
            qa.y = bf16pk(c[0][2], c[1][0]);
            qa.z = bf16pk(c[1][1], c[1][2]);
            qa.w = bf16pk(c[2][0], c[2][1]);
            qb.x = bf16pk(c[2][2], c[3][0]);
            qb.y = bf16pk(c[3][1], c[3][2]);
            qb.z = 0u; qb.w = 0u;
            uint4* qd = (uint4*)(ws + OFF_ST) + (size_t)idx*2;
            qd[0] = qa; qd[1] = qb;
        }
    } else {
        // coarse point prepass
        int pt = (bid - 1 - QT_BLOCKS)*256 + t;
        int ray = pt / S_;
        int j = pt - ray*S_;
        float depth = 0.5f + (float)j*DELTA_ + noise[pt]*DELTA_;
        ws[OFF_DC + pt] = depth;
        float px = fmaf(depth, rd[ray*3+0], ro[ray*3+0]);
        float py = fmaf(depth, rd[ray*3+1], ro[ray*3+1]);
        float pz = fmaf(depth, rd[ray*3+2], ro[ray*3+2]);
        ((float4*)(ws + OFF_PTS))[pt] = make_float4(px, py, pz, depth);
    }
}

// ---- gather helpers: projection+load (phase A) and bilerp+pack (phase B) ----
__device__ __forceinline__ void proj_load(
    const f32x4 Pa, const f32x4 Pb, const f32x4 Pc,
    const uint4* __restrict__ stp, float px, float py, float pz,
    uint4& qa, uint2& qb, float& wx, float& wy, unsigned& gpk)
{
    float c0 = fmaf(Pa.x,px, fmaf(Pa.y,py, fmaf(Pa.z,pz, Pa.w)));
    float c1 = fmaf(Pb.x,px, fmaf(Pb.y,py, fmaf(Pb.z,pz, Pb.w)));
    float c2 = fmaf(Pc.x,px, fmaf(Pc.y,py, fmaf(Pc.z,pz, Pc.w)));
    float rz = __builtin_amdgcn_rcpf(c2);
    float gx = fminf(fmaxf((1.0254f*c0 + 0.5f*c2)*rz, 0.f), 1.f)*2.f - 1.f;
    float gy = fminf(fmaxf((1.0254f*c1 + 0.5f*c2)*rz, 0.f), 1.f)*2.f - 1.f;
    float ixp = ((gx + 1.f)*64.f - 1.f)*0.5f + 1.f;
    float iyp = ((gy + 1.f)*64.f - 1.f)*0.5f + 1.f;
    float xf = floorf(ixp), yf = floorf(iyp);
    wx = ixp - xf; wy = iyp - yf;
    int x0p = (int)xf, y0p = (int)yf;               // [0,64]
    const uint4* ep = stp + (unsigned)(y0p*QT_XS + x0p)*2u;
    qa = ep[0];
    qb = *(const uint2*)(ep + 1);
    gpk = bf16pk(gx, gy);
}

__device__ __forceinline__ void bilerp_pack(
    const uint4 qa, const uint2 qb, float wx, float wy, unsigned gpk, uint4& av)
{
    float wy0 = 1.f - wy, wy1 = wy;
    float w0x = 1.f - wx, w1x = wx;
    float tl0 = fmaf(wy0, bflo(qa.x), wy1*bflo(qa.w));
    float tl1 = fmaf(wy0, bfhi(qa.x), wy1*bfhi(qa.w));
    float tl2 = fmaf(wy0, bflo(qa.y), wy1*bflo(qb.x));
    float tr0 = fmaf(wy0, bfhi(qa.y), wy1*bfhi(qb.x));
    float tr1 = fmaf(wy0, bflo(qa.z), wy1*bflo(qb.y));
    float tr2 = fmaf(wy0, bfhi(qa.z), wy1*bfhi(qb.y));
    float f0 = fmaf(w0x, tl0, w1x*tr0);
    float f1 = fmaf(w0x, tl1, w1x*tr1);
    float f2 = fmaf(w0x, tl2, w1x*tr2);
    av.x = bf16pk(f0, f1);
    av.y = ((unsigned)bf16rne(f2)) | (gpk << 16);   // [f2, gx]
    av.z = gpk >> 16;                               // [gy, 0]
    av.w = 0u;
}

// ---- kernel 2: FUSED gather + MFMA MLP (quad-texel loads, 2-stage pipeline) ----
__global__ __launch_bounds__(256) void k_fused(
    const uint4* __restrict__ stq, const float4* __restrict__ pts,
    const float* __restrict__ poses,
    const float* __restrict__ b1, const unsigned short* __restrict__ w1e,
    const unsigned short* __restrict__ w2e, const float* __restrict__ b2e,
    unsigned short* __restrict__ colors, float* __restrict__ dens)
{
    __shared__ __align__(16) unsigned short smem[4][4608];
    __shared__ __align__(16) float pl[384];
    int tid = threadIdx.x;
    int wv = tid >> 6, lane = tid & 63;
    int n = lane & 15, q = lane >> 4;
    int wlocal = blockIdx.x*256 + wv*64;
    int bq = (wlocal >= NPTS/2) ? 32 : 0;   // batch plane-base; blocks never straddle

    for (int i = tid; i < 384; i += 256) pl[i] = poses[i];
    __syncthreads();

    float px[4], py[4], pz[4];
#pragma unroll
    for (int t = 0; t < 4; t++) {
        float4 pv = pts[wlocal + t*16 + n];
        px[t] = pv.x; py[t] = pv.y; pz[t] = pv.z;
    }

    f32x4 acc[4][4];
#pragma unroll
    for (int t = 0; t < 4; t++)
#pragma unroll
        for (int nt = 0; nt < 4; nt++) {
            float bv = b1[nt*16 + n];
            acc[t][nt] = (f32x4){bv, bv, bv, bv};
        }

#pragma unroll
    for (int s = 0; s < 8; s++) {
        int plane = s*4 + q;
        const f32x4* Pq = (const f32x4*)(pl + plane*12);
        f32x4 Pa = Pq[0], Pb = Pq[1], Pc = Pq[2];
        const uint4* stp = stq + (unsigned)(bq + plane)*(unsigned)(QT_PLANE*2);
        union { short8 s8; uint4 u; } av[4];
        {   // 2-stage pipeline: 2 loads in flight while next 2 projections issue
            uint4 qa0, qa1; uint2 qb0, qb1;
            float wxa, wya, wxb, wyb; unsigned g0, g1;
            proj_load(Pa, Pb, Pc, stp, px[0], py[0], pz[0], qa0, qb0, wxa, wya, g0);
            proj_load(Pa, Pb, Pc, stp, px[1], py[1], pz[1], qa1, qb1, wxb, wyb, g1);
            bilerp_pack(qa0, qb0, wxa, wya, g0, av[0].u);
            bilerp_pack(qa1, qb1, wxb, wyb, g1, av[1].u);
            proj_load(Pa, Pb, Pc, stp, px[2], py[2], pz[2], qa0, qb0, wxa, wya, g0);
            proj_load(Pa, Pb, Pc, stp, px[3], py[3], pz[3], qa1, qb1, wxb, wyb, g1);
            bilerp_pack(qa0, qb0, wxa, wya, g0, av[2].u);
            bilerp_pack(qa1, qb1, wxb, wyb, g1, av[3].u);
        }
#pragma unroll
        for (int nt = 0; nt < 4; nt++) {
            short8 bfw = *(const short8*)(w1e + (nt*16 + n)*256 + s*32 + q*8);
#pragma unroll
            for (int t = 0; t < 4; t++)
                acc[t][nt] = __builtin_amdgcn_mfma_f32_16x16x32_bf16(av[t].s8, bfw, acc[t][nt], 0, 0, 0);
        }
    }

    unsigned short* ht = &smem[wv][0];
#pragma unroll
    for (int t = 0; t < 4; t++)
#pragma unroll
        for (int nt = 0; nt < 4; nt++)
#pragma unroll
            for (int r = 0; r < 4; r++) {
                float hv = softplus_f(acc[t][nt][r]);
                ht[(t*16 + q*4 + r)*72 + nt*16 + n] = bf16rne(hv);
            }
    short8 a2[4][2];
#pragma unroll
    for (int t = 0; t < 4; t++)
#pragma unroll
        for (int s2 = 0; s2 < 2; s2++)
            a2[t][s2] = *(const short8*)(ht + (t*16 + n)*72 + s2*32 + q*8);
    // no __syncthreads: aliasing is wave-local; DS pipe in-order per wave

    f32x4 acc2[4][3];
#pragma unroll
    for (int t = 0; t < 4; t++)
#pragma unroll
        for (int nt = 0; nt < 3; nt++) {
            float bv = b2e[nt*16 + n];
            acc2[t][nt] = (f32x4){bv, bv, bv, bv};
        }
    short8 b2f[3][2];
#pragma unroll
    for (int nt = 0; nt < 3; nt++)
#pragma unroll
        for (int s2 = 0; s2 < 2; s2++)
            b2f[nt][s2] = *(const short8*)(w2e + (nt*16 + n)*64 + s2*32 + q*8);
#pragma unroll
    for (int t = 0; t < 4; t++)
#pragma unroll
        for (int nt = 0; nt < 3; nt++)
#pragma unroll
            for (int s2 = 0; s2 < 2; s2++)
                acc2[t][nt] = __builtin_amdgcn_mfma_f32_16x16x32_bf16(a2[t][s2], b2f[nt][s2], acc2[t][nt], 0, 0, 0);

    float* ot = (float*)&smem[wv][0];
#pragma unroll
    for (int t = 0; t < 4; t++)
#pragma unroll
        for (int nt = 0; nt < 3; nt++) {
            int col = nt*16 + n;
#pragma unroll
            for (int r = 0; r < 4; r++) {
                float v = acc2[t][nt][r];
                int row = t*16 + q*4 + r;
                if (col == 0) ot[row*34 + 32] = v;
                else if (col <= 32) {
                    float sg = sigmoid_f(v);
                    ot[row*34 + (col-1)] = fmaf(sg, 1.002f, -0.001f);
                }
            }
        }
    unsigned* cgu = (unsigned*)(colors + (size_t)wlocal*32);
    for (int i = 0; i < 16; i++) {
        int ui = i*64 + lane;
        int pt = ui >> 4, ch = (ui & 15)*2;
        cgu[ui] = bf16pk(ot[pt*34 + ch], ot[pt*34 + ch + 1]);
    }
    dens[wlocal + lane] = ot[lane*34 + 32];
}

// ---- kernel 3: coarse march + pdf + importance samples + fine point gen ----
__global__ __launch_bounds__(256) void k_imp(const float* __restrict__ u, float* ws,
                                             const float* __restrict__ ro,
                                             const float* __restrict__ rd,
                                             float4* __restrict__ pts) {
    __shared__ float zl[4][48];
    __shared__ float cdfl[4][46];
    int tid = threadIdx.x;
    int wv = tid >> 6, lane = tid & 63;
    int r = blockIdx.x*4 + wv;
    const float* z   = ws + OFF_DC + (size_t)r*48;
    const float* den = ws + OFF_SC + (size_t)r*48;
    float zv = 0.f, dv = 0.f;
    if (lane < 48) { zv = z[lane]; dv = den[lane]; zl[wv][lane] = zv; }
    float zn  = __shfl_down(zv, 1);
    float dnn = __shfl_down(dv, 1);
    float alpha = 0.f, f = 1.f;
    if (lane < 47) {
        float sp = softplus_f(0.5f*(dv + dnn) - 1.f);
        alpha = 1.f - __expf(-sp*(zn - zv));
        f = 1.f - alpha + 1e-10f;
    }
    float v = f;
    for (int off = 1; off < 64; off <<= 1) { float o = __shfl_up(v, off); if (lane >= off) v *= o; }
    float T = __shfl_up(v, 1); if (lane == 0) T = 1.f;
    float w = alpha*T;
    float wn1 = __shfl_down(w, 1), wn2 = __shfl_down(w, 2);
    float pw = 0.f;
    if (lane < 45) pw = 0.5f*(fmaxf(w, wn1) + fmaxf(wn1, wn2)) + 0.01f + 1e-5f;
    float s = pw;
    for (int off = 1; off < 64; off <<= 1) { float o = __shfl_up(s, off); if (lane >= off) s += o; }
    float csum = __shfl(s, 63);
    if (lane < 45) cdfl[wv][lane+1] = s/csum;
    if (lane == 63) cdfl[wv][0] = 0.f;
    __syncthreads();
    if (lane < 48) {
        float uu = u[(size_t)r*48 + lane];
        int lo = 0, hi = 46;
        while (lo < hi) { int mid = (lo+hi)>>1; if (uu >= cdfl[wv][mid]) lo = mid+1; else hi = mid; }
        int below = max(lo-1, 0), above = min(lo, 45);
        float cb = cdfl[wv][below], ca = cdfl[wv][above];
        float zb = zl[wv][below],   za = zl[wv][above];
        float dn2 = ca - cb; if (dn2 < 1e-5f) dn2 = 1.f;
        float df_s = zb + (uu - cb)/dn2*(za - zb);
        ws[OFF_DF + (size_t)r*48 + lane] = df_s;
        float fx = fmaf(df_s, rd[r*3+0], ro[r*3+0]);
        float fy = fmaf(df_s, rd[r*3+1], ro[r*3+1]);
        float fz = fmaf(df_s, rd[r*3+2], ro[r*3+2]);
        pts[(size_t)r*48 + lane] = make_float4(fx, fy, fz, df_s);
    }
}

// ---- kernel 5: fused sort + march + color accumulation (wave per ray) ----
__global__ __launch_bounds__(256) void k_final(float* __restrict__ out, const float* __restrict__ ws,
                                               const unsigned short* __restrict__ cC,
                                               const unsigned short* __restrict__ cF)
{
    __shared__ float kd[4][96];
    __shared__ float kden[4][96];
    __shared__ float sdl[4][96];
    __shared__ float sdenl[4][96];
    __shared__ int   sidxl[4][96];
    __shared__ float warr[4][96];
    __shared__ float earr[4][96];
    int tid = threadIdx.x;
    int wv = tid >> 6, lane = tid & 63;
    int r = blockIdx.x*4 + wv;
    const float* dc = ws + OFF_DC + (size_t)r*48;
    const float* df = ws + OFF_DF + (size_t)r*48;
    const float* sc = ws + OFF_SC + (size_t)r*48;
    const float* sf = ws + OFF_SF + (size_t)r*48;
    for (int i = lane; i < 96; i += 64) {
        float d, dn;
        if (i < 48) { d = dc[i]; dn = sc[i]; }
        else        { d = df[i-48]; dn = sf[i-48]; }
        kd[wv][i] = d; kden[wv][i] = dn;
    }
    __syncthreads();
    for (int i = lane; i < 96; i += 64) {
        float d = kd[wv][i];
        int rank = 0;
        for (int j = 0; j < 96; j++) {
            float dj = kd[wv][j];
            rank += (int)((dj < d) | ((dj == d) & (j < i)));
        }
        sdl[wv][rank] = d; sdenl[wv][rank] = kden[wv][i]; sidxl[wv][rank] = i;
    }
    __syncthreads();
    int i2 = 2*lane;
    float a0=0.f, f0=1.f, a1=0.f, f1=1.f, d0=0.f, d1=0.f, d2=0.f;
    if (i2 < 95) {
        d0 = sdl[wv][i2]; d1 = sdl[wv][i2+1];
        float sp = softplus_f(0.5f*(sdenl[wv][i2] + sdenl[wv][i2+1]) - 1.f);
        a0 = 1.f - __expf(-sp*(d1 - d0)); f0 = 1.f - a0 + 1e-10f;
    }
    if (i2+1 < 95) {
        d2 = sdl[wv][i2+2];
        float sp = softplus_f(0.5f*(sdenl[wv][i2+1] + sdenl[wv][i2+2]) - 1.f);
        a1 = 1.f - __expf(-sp*(d2 - d1)); f1 = 1.f - a1 + 1e-10f;
    }
    float p = f0*f1, v = p;
    for (int off = 1; off < 64; off <<= 1) { float o = __shfl_up(v, off); if (lane >= off) v *= o; }
    float excl = __shfl_up(v, 1); if (lane == 0) excl = 1.f;
    float w0 = a0*excl, w1 = a1*excl*f0;
    if (i2   < 96) warr[wv][i2]   = w0;
    if (i2+1 < 96) warr[wv][i2+1] = w1;
    float wsm = w0 + w1;
    float dsm = w0*0.5f*(d0+d1) + w1*0.5f*(d1+d2);
    for (int off = 32; off; off >>= 1) { wsm += __shfl_xor(wsm, off); dsm += __shfl_xor(dsm, off); }
    __syncthreads();
    for (int i = lane; i < 96; i += 64) {
        float wp = (i > 0)  ? warr[wv][i-1] : 0.f;
        float wc = (i < 95) ? warr[wv][i]   : 0.f;
        earr[wv][sidxl[wv][i]] = 0.5f*(wp + wc);
    }
    __syncthreads();
    int ch = lane & 31, half = lane >> 5;
    const unsigned short* cbase = (half ? cF : cC) + ((size_t)r*48)*32 + ch;
    const float* eb = &earr[wv][half*48];
    float a = 0.f;
    for (int jj = 0; jj < 48; jj++)
        a = fmaf(eb[jj], bf2f(cbase[(size_t)jj*32]), a);
    a += __shfl_xor(a, 32);
    if (lane < 32) out[(size_t)r*34 + lane] = 2.f*a - 1.f;
    if (lane == 0) {
        float gmn = ws[OFF_MINMAX];
        float gmx = ws[OFF_MINMAX + 1];
        float depth = dsm/wsm;
        if (depth != depth) depth = __builtin_inff();
        depth = fminf(fmaxf(depth, gmn), gmx);
        out[(size_t)r*34 + 32] = depth;
        out[(size_t)r*34 + 33] = wsm;
    }
}

extern "C" void kernel_launch(void* const* d_in, const int* in_sizes, int n_in,
                              void* d_out, int out_size, void* d_ws, size_t ws_size,
                              hipStream_t stream) {
    const float* planes = (const float*)d_in[0];
    const float* ro     = (const float*)d_in[1];
    const float* rd     = (const float*)d_in[2];
    const float* noise  = (const float*)d_in[3];
    const float* u      = (const float*)d_in[4];
    const float* W1     = (const float*)d_in[5];
    const float* b1     = (const float*)d_in[6];
    const float* W2     = (const float*)d_in[7];
    const float* b2     = (const float*)d_in[8];
    float* ws  = (float*)d_ws;
    float* out = (float*)d_out;
    const unsigned short* w1e = (const unsigned short*)(ws + OFF_W1E);
    const unsigned short* w2e = (const unsigned short*)(ws + OFF_W2E);
    const uint4* stq = (const uint4*)(ws + OFF_ST);
    float4* pts = (float4*)(ws + OFF_PTS);
    unsigned short* cC = (unsigned short*)(ws + OFF_CC);
    unsigned short* cF = (unsigned short*)(ws + OFF_CF);

    hipLaunchKernelGGL(k_mm,    dim3(1), dim3(1024), 0, stream, noise, ws);
    hipLaunchKernelGGL(k_setup, dim3(SETUP_GRID), dim3(256), 0, stream,
                       ws, W1, W2, b2, planes, noise, ro, rd);
    hipLaunchKernelGGL(k_fused, dim3(NPTS/256), dim3(256), 0, stream,
                       stq, pts, ws + OFF_POSES, b1, w1e, w2e, ws + OFF_B2E, cC, ws + OFF_SC);
    hipLaunchKernelGGL(k_imp, dim3(NRAYS/4), dim3(256), 0, stream, u, ws, ro, rd, pts);
    hipLaunchKernelGGL(k_fused, dim3(NPTS/256), dim3(256), 0, stream,
                       stq, pts, ws + OFF_POSES, b1, w1e, w2e, ws + OFF_B2E, cF, ws + OFF_SF);
    hipLaunchKernelGGL(k_final, dim3(NRAYS/4), dim3(256), 0, stream, out, ws, cC, cF);
}

// Round 4
// 268.653 us; speedup vs baseline: 1.1698x; 1.0756x over previous
//
#include <hip/hip_runtime.h>
#include <math.h>

#define B_   2
#define N_   4096
#define S_   48
#define NPL  32
#define NRAYS (B_*N_)          // 8192
#define NPTS  (NRAYS*S_)       // 393216
#define DELTA_ (2.0f/47.0f)
#define NBLK_FUSED (NPTS/256)  // 1536

// quad-texel table: entry (plane, y0, x0) = 2x2 bf16 texel stencil, 32B
#define QT_XS    66                     // x stride (x0 in [0,64], 1 pad col)
#define QT_YS    65                     // y0 in [0,64]
#define QT_PLANE (QT_YS*QT_XS)          // 4290 entries per plane
#define QT_TOTAL (64*QT_PLANE)          // 274560 entries (2 batches x 32 planes)
#define SETUP_GRID (2 + 64 + NPTS/256)  // init + minmax + plane-repack + coarse pts

// ---- workspace layout (float offsets) ----
#define OFF_POSES  0                    // 384
#define OFF_MINMAX 384                  // 2 floats (gmin, gmax)
#define OFF_W1E    512                  // 64*256 bf16 = 8192 floats
#define OFF_W2E    8704                 // 48*64 bf16
#define OFF_B2E    10240                // 48 floats
#define OFF_ST     16384                // quad table: QT_TOTAL*8 floats -> ends 2212864
#define OFF_PTS    2212864              // float4 per point: NPTS*4 -> ends 3785728
#define OFF_DC     3785728              // depths_c [NPTS]
#define OFF_DF     4178944
#define OFF_SC     4572160
#define OFF_SF     4965376
#define OFF_CC     5358592              // colors_c bf16 [NPTS*32] -> ends 11650048
#define OFF_CF     11650048             // colors_f bf16 -> ends 17941504

typedef __attribute__((ext_vector_type(8))) short short8;
typedef __attribute__((ext_vector_type(4))) float f32x4;

__device__ __forceinline__ float softplus_f(float x) {
    return fmaxf(x, 0.f) + __logf(1.f + __expf(-fabsf(x)));
}
__device__ __forceinline__ float sigmoid_f(float x) {
    return __builtin_amdgcn_rcpf(1.f + __expf(-x));
}
__device__ __forceinline__ unsigned short bf16rne(float x) {
    unsigned u = __float_as_uint(x);
    u += 0x7FFFu + ((u >> 16) & 1u);
    return (unsigned short)(u >> 16);
}
__device__ __forceinline__ unsigned bf16pk(float lo, float hi) {
    return (unsigned)bf16rne(lo) | ((unsigned)bf16rne(hi) << 16);
}
__device__ __forceinline__ float bf2f(unsigned short v) {
    return __uint_as_float(((unsigned)v) << 16);
}
__device__ __forceinline__ float bflo(unsigned u) { return __uint_as_float(u << 16); }
__device__ __forceinline__ float bfhi(unsigned u) { return __uint_as_float(u & 0xffff0000u); }

__device__ void mul3(const double* a, const double* b, double* o) {
    for (int i = 0; i < 3; i++)
        for (int j = 0; j < 3; j++) {
            double s = 0.0;
            for (int k = 0; k < 3; k++) s += a[i*3+k]*b[k*3+j];
            o[i*3+j] = s;
        }
}

// ---- kernel 0: setup ----
// bid 0: poses + weight repack; bid 1: depth minmax;
// bid 2..65: plane-staged quad-texel repack; bid 66..: coarse point prepass.
__global__ __launch_bounds__(256) void k_setup(
    float* ws, const float* __restrict__ W1,
    const float* __restrict__ W2, const float* __restrict__ b2,
    const float* __restrict__ planes, const float* __restrict__ noise,
    const float* __restrict__ ro, const float* __restrict__ rd)
{
    __shared__ unsigned short texs[3][4096];    // 24 KB (repack branch)
    __shared__ float smn[4], smx[4];
    int bid = blockIdx.x;
    int t = threadIdx.x;
    if (bid == 0) {
        // poses (double math, faithful)
        if (t < 32) {
            double y = 1.0 - (t/31.0)*2.0;
            double rr = sqrt(fmax(1.0 - y*y, 0.0));
            double golden = M_PI*(sqrt(5.0) - 1.0);
            double th = golden*(double)t;
            double x = cos(th)*rr, z = sin(th)*rr;
            double phi   = atan2(z, sqrt(x*x + y*y));   // radians treated as degrees (faithful)
            double theta = atan2(y, x);
            double p  = phi/180.0*M_PI;
            double tt = theta/180.0*M_PI;
            double e  = 90.0/180.0*M_PI;
            double cp = cos(p), sp = sin(p), ct = cos(tt), st = sin(tt);
            double ce = cos(e), se = sin(e);
            double Ph[9] = {1,0,0,  0,cp,-sp,  0,sp,cp};
            double Th[9] = {ct,0,-st,  0,1,0,  st,0,ct};
            double Et[9] = {ce,se,0,  -se,ce,0,  0,0,1};
            double M3[9] = {-1,0,0,  0,0,1,  0,1,0};
            double A[9], Bm[9], R[9];
            mul3(Th, Ph, A);
            mul3(Et, A, Bm);
            mul3(M3, Bm, R);
            double radius = -1.307;
            double tv0 = radius*R[2], tv1 = radius*R[5], tv2 = radius*R[8];
            double Rf[9] = {-R[0],R[1],R[2], -R[3],R[4],R[5], -R[6],R[7],R[8]};
            float* P = ws + OFF_POSES + t*12;
            for (int j = 0; j < 3; j++) {
                double r0 = Rf[0*3+j], r1 = Rf[1*3+j], r2 = Rf[2*3+j];
                P[j*4+0] = (float)r0;
                P[j*4+1] = (float)r1;
                P[j*4+2] = (float)r2;
                P[j*4+3] = (float)(-(r0*tv0 + r1*tv1 + r2*tv2));
            }
        }
        unsigned short* w1e = (unsigned short*)(ws + OFF_W1E);
        for (int idx = t; idx < 64*256; idx += 256) {
            int n = idx >> 8, k = idx & 255;
            int p = k >> 3, f = k & 7;
            float v = 0.f;
            if (f < 3)      v = W1[(3*p+f)*64 + n];
            else if (f < 5) v = W1[(96 + 2*p + (f-3))*64 + n];
            w1e[idx] = bf16rne(v);
        }
        unsigned short* w2e = (unsigned short*)(ws + OFF_W2E);
        for (int idx = t; idx < 48*64; idx += 256) {
            int n = idx >> 6, k = idx & 63;
            float v = (n < 33) ? W2[k*33 + n] : 0.f;
            w2e[idx] = bf16rne(v);
        }
        for (int idx = t; idx < 48; idx += 256)
            ws[OFF_B2E + idx] = (idx < 33) ? b2[idx] : 0.f;
    } else if (bid == 1) {
        // depth minmax over noise col 0 / col 47
        float mn = 1e30f, mx = -1e30f;
        for (int r = t; r < NRAYS; r += 256) {
            float n0  = noise[(size_t)r*48];
            float n47 = noise[(size_t)r*48 + 47];
            mn = fminf(mn, 0.5f + n0*DELTA_);
            mx = fmaxf(mx, 0.5f + 47.f*DELTA_ + n47*DELTA_);
        }
        for (int off = 32; off > 0; off >>= 1) {
            mn = fminf(mn, __shfl_down(mn, off));
            mx = fmaxf(mx, __shfl_down(mx, off));
        }
        if ((t & 63) == 0) { smn[t >> 6] = mn; smx[t >> 6] = mx; }
        __syncthreads();
        if (t == 0) {
            ws[OFF_MINMAX]     = fminf(fminf(smn[0], smn[1]), fminf(smn[2], smn[3]));
            ws[OFF_MINMAX + 1] = fmaxf(fmaxf(smx[0], smx[1]), fmaxf(smx[2], smx[3]));
        }
    } else if (bid < 66) {
        // plane-staged quad repack: one block per global plane; each texel read ONCE.
        int bp = bid - 2;                         // global plane 0..63
        int b = bp >> 5, p = bp & 31;
        const float* base = planes + ((size_t)b*96 + 3*p)*4096;
        for (int i = t; i < 4096; i += 256) {
            texs[0][i] = bf16rne(base[i]);
            texs[1][i] = bf16rne(base[4096 + i]);
            texs[2][i] = bf16rne(base[8192 + i]);
        }
        __syncthreads();
        uint4* qd = (uint4*)(ws + OFF_ST) + (size_t)bp*QT_PLANE*2;
        for (int e = t; e < QT_PLANE; e += 256) {
            int y0 = e / QT_XS, x0 = e - y0*QT_XS;
            unsigned short cs[4][3] = {{0,0,0},{0,0,0},{0,0,0},{0,0,0}};
            if (x0 <= 64) {
#pragma unroll
                for (int dy = 0; dy < 2; dy++) {
                    int jy = y0 - 1 + dy;
                    if (jy < 0 || jy > 63) continue;
#pragma unroll
                    for (int dx = 0; dx < 2; dx++) {
                        int jx = x0 - 1 + dx;
                        if (jx < 0 || jx > 63) continue;
                        int ti = jy*64 + jx;
                        cs[dy*2+dx][0] = texs[0][ti];
                        cs[dy*2+dx][1] = texs[1][ti];
                        cs[dy*2+dx][2] = texs[2][ti];
                    }
                }
            }
            uint4 qa, qb;
            qa.x = (unsigned)cs[0][0] | ((unsigned)cs[0][1] << 16);
            qa.y = (unsigned)cs[0][2] | ((unsigned)cs[1][0] << 16);
            qa.z = (unsigned)cs[1][1] | ((unsigned)cs[1][2] << 16);
            qa.w = (unsigned)cs[2][0] | ((unsigned)cs[2][1] << 16);
            qb.x = (unsigned)cs[2][2] | ((unsigned)cs[3][0] << 16);
            qb.y = (unsigned)cs[3][1] | ((unsigned)cs[3][2] << 16);
            qb.z = 0u; qb.w = 0u;
            qd[(size_t)e*2]     = qa;
            qd[(size_t)e*2 + 1] = qb;
        }
    } else {
        // coarse point prepass
        int pt = (bid - 66)*256 + t;
        int ray = pt / S_;
        int j = pt - ray*S_;
        float depth = 0.5f + (float)j*DELTA_ + noise[pt]*DELTA_;
        ws[OFF_DC + pt] = depth;
        float px = fmaf(depth, rd[ray*3+0], ro[ray*3+0]);
        float py = fmaf(depth, rd[ray*3+1], ro[ray*3+1]);
        float pz = fmaf(depth, rd[ray*3+2], ro[ray*3+2]);
        ((float4*)(ws + OFF_PTS))[pt] = make_float4(px, py, pz, depth);
    }
}

// ---- gather helpers: projection+load (phase A) and bilerp+pack (phase B) ----
__device__ __forceinline__ void proj_load(
    const f32x4 Pa, const f32x4 Pb, const f32x4 Pc,
    const uint4* __restrict__ stp, float px, float py, float pz,
    uint4& qa, uint2& qb, float& wx, float& wy, unsigned& gpk)
{
    float c0 = fmaf(Pa.x,px, fmaf(Pa.y,py, fmaf(Pa.z,pz, Pa.w)));
    float c1 = fmaf(Pb.x,px, fmaf(Pb.y,py, fmaf(Pb.z,pz, Pb.w)));
    float c2 = fmaf(Pc.x,px, fmaf(Pc.y,py, fmaf(Pc.z,pz, Pc.w)));
    float rz = __builtin_amdgcn_rcpf(c2);
    float gx = fminf(fmaxf((1.0254f*c0 + 0.5f*c2)*rz, 0.f), 1.f)*2.f - 1.f;
    float gy = fminf(fmaxf((1.0254f*c1 + 0.5f*c2)*rz, 0.f), 1.f)*2.f - 1.f;
    float ixp = ((gx + 1.f)*64.f - 1.f)*0.5f + 1.f;
    float iyp = ((gy + 1.f)*64.f - 1.f)*0.5f + 1.f;
    float xf = floorf(ixp), yf = floorf(iyp);
    wx = ixp - xf; wy = iyp - yf;
    int x0p = (int)xf, y0p = (int)yf;               // [0,64]
    const uint4* ep = stp + (unsigned)(y0p*QT_XS + x0p)*2u;
    qa = ep[0];
    qb = *(const uint2*)(ep + 1);
    gpk = bf16pk(gx, gy);
}

__device__ __forceinline__ void bilerp_pack(
    const uint4 qa, const uint2 qb, float wx, float wy, unsigned gpk, uint4& av)
{
    float wy0 = 1.f - wy, wy1 = wy;
    float w0x = 1.f - wx, w1x = wx;
    float tl0 = fmaf(wy0, bflo(qa.x), wy1*bflo(qa.w));
    float tl1 = fmaf(wy0, bfhi(qa.x), wy1*bfhi(qa.w));
    float tl2 = fmaf(wy0, bflo(qa.y), wy1*bflo(qb.x));
    float tr0 = fmaf(wy0, bfhi(qa.y), wy1*bfhi(qb.x));
    float tr1 = fmaf(wy0, bflo(qa.z), wy1*bflo(qb.y));
    float tr2 = fmaf(wy0, bfhi(qa.z), wy1*bfhi(qb.y));
    float f0 = fmaf(w0x, tl0, w1x*tr0);
    float f1 = fmaf(w0x, tl1, w1x*tr1);
    float f2 = fmaf(w0x, tl2, w1x*tr2);
    av.x = bf16pk(f0, f1);
    av.y = ((unsigned)bf16rne(f2)) | (gpk << 16);   // [f2, gx]
    av.z = gpk >> 16;                               // [gy, 0]
    av.w = 0u;
}

// ---- kernel 2: FUSED gather + MFMA MLP ----
// Per-t-tile epilogue: LDS scratch = 16 rows not 64 -> 10.8 KB/block (was 38.4).
// XCD swizzle: each XCD gets 192 consecutive blocks = one batch half's table (4.4MB ~ L2).
__global__ __launch_bounds__(256) void k_fused(
    const uint4* __restrict__ stq, const float4* __restrict__ pts,
    const float* __restrict__ poses,
    const float* __restrict__ b1, const unsigned short* __restrict__ w1e,
    const unsigned short* __restrict__ w2e, const float* __restrict__ b2e,
    unsigned short* __restrict__ colors, float* __restrict__ dens)
{
    __shared__ __align__(16) unsigned short smem[4][1152];   // per-wave 16x72 shorts
    __shared__ __align__(16) float pl[384];
    int tid = threadIdx.x;
    int wv = tid >> 6, lane = tid & 63;
    int n = lane & 15, q = lane >> 4;
    int bid = blockIdx.x;
    int swz = (bid & 7)*(NBLK_FUSED/8) + (bid >> 3);        // bijective, 1536 % 8 == 0
    int wlocal = swz*256 + wv*64;
    int bq = (wlocal >= NPTS/2) ? 32 : 0;   // batch plane-base; blocks never straddle

    for (int i = tid; i < 384; i += 256) pl[i] = poses[i];
    __syncthreads();

    float px[4], py[4], pz[4];
#pragma unroll
    for (int t = 0; t < 4; t++) {
        float4 pv = pts[wlocal + t*16 + n];
        px[t] = pv.x; py[t] = pv.y; pz[t] = pv.z;
    }

    f32x4 acc[4][4];
#pragma unroll
    for (int t = 0; t < 4; t++)
#pragma unroll
        for (int nt = 0; nt < 4; nt++) {
            float bv = b1[nt*16 + n];
            acc[t][nt] = (f32x4){bv, bv, bv, bv};
        }

#pragma unroll
    for (int s = 0; s < 8; s++) {
        int plane = s*4 + q;
        const f32x4* Pq = (const f32x4*)(pl + plane*12);
        f32x4 Pa = Pq[0], Pb = Pq[1], Pc = Pq[2];
        const uint4* stp = stq + (unsigned)(bq + plane)*(unsigned)(QT_PLANE*2);
        union { short8 s8; uint4 u; } av[4];
        {   // 2-stage pipeline: 2 loads in flight while next 2 projections issue
            uint4 qa0, qa1; uint2 qb0, qb1;
            float wxa, wya, wxb, wyb; unsigned g0, g1;
            proj_load(Pa, Pb, Pc, stp, px[0], py[0], pz[0], qa0, qb0, wxa, wya, g0);
            proj_load(Pa, Pb, Pc, stp, px[1], py[1], pz[1], qa1, qb1, wxb, wyb, g1);
            bilerp_pack(qa0, qb0, wxa, wya, g0, av[0].u);
            bilerp_pack(qa1, qb1, wxb, wyb, g1, av[1].u);
            proj_load(Pa, Pb, Pc, stp, px[2], py[2], pz[2], qa0, qb0, wxa, wya, g0);
            proj_load(Pa, Pb, Pc, stp, px[3], py[3], pz[3], qa1, qb1, wxb, wyb, g1);
            bilerp_pack(qa0, qb0, wxa, wya, g0, av[2].u);
            bilerp_pack(qa1, qb1, wxb, wyb, g1, av[3].u);
        }
#pragma unroll
        for (int nt = 0; nt < 4; nt++) {
            short8 bfw = *(const short8*)(w1e + (nt*16 + n)*256 + s*32 + q*8);
#pragma unroll
            for (int t = 0; t < 4; t++)
                acc[t][nt] = __builtin_amdgcn_mfma_f32_16x16x32_bf16(av[t].s8, bfw, acc[t][nt], 0, 0, 0);
        }
    }

    // layer-2 weights (shared across t-tiles)
    short8 b2f[3][2];
#pragma unroll
    for (int nt = 0; nt < 3; nt++)
#pragma unroll
        for (int s2 = 0; s2 < 2; s2++)
            b2f[nt][s2] = *(const short8*)(w2e + (nt*16 + n)*64 + s2*32 + q*8);

    unsigned short* ht = &smem[wv][0];
#pragma unroll
    for (int t = 0; t < 4; t++) {
        // h-tile (16 pts) -> LDS (bf16), wave-local transpose
#pragma unroll
        for (int nt = 0; nt < 4; nt++)
#pragma unroll
            for (int r = 0; r < 4; r++) {
                float hv = softplus_f(acc[t][nt][r]);
                ht[(q*4 + r)*72 + nt*16 + n] = bf16rne(hv);
            }
        short8 a2[2];
#pragma unroll
        for (int s2 = 0; s2 < 2; s2++)
            a2[s2] = *(const short8*)(ht + n*72 + s2*32 + q*8);
        // no __syncthreads: aliasing is wave-local; DS pipe in-order per wave

        f32x4 acc2[3];
#pragma unroll
        for (int nt = 0; nt < 3; nt++) {
            float bv = b2e[nt*16 + n];
            acc2[nt] = (f32x4){bv, bv, bv, bv};
        }
#pragma unroll
        for (int nt = 0; nt < 3; nt++)
#pragma unroll
            for (int s2 = 0; s2 < 2; s2++)
                acc2[nt] = __builtin_amdgcn_mfma_f32_16x16x32_bf16(a2[s2], b2f[nt][s2], acc2[nt], 0, 0, 0);

        float* ot = (float*)ht;                      // reuse same wave-local region
#pragma unroll
        for (int nt = 0; nt < 3; nt++) {
            int col = nt*16 + n;
#pragma unroll
            for (int r = 0; r < 4; r++) {
                float v = acc2[nt][r];
                int row = q*4 + r;
                if (col == 0) ot[row*34 + 32] = v;
                else if (col <= 32) {
                    float sg = sigmoid_f(v);
                    ot[row*34 + (col-1)] = fmaf(sg, 1.002f, -0.001f);
                }
            }
        }
        unsigned* cgu = (unsigned*)(colors + (size_t)(wlocal + t*16)*32);
#pragma unroll
        for (int i = 0; i < 4; i++) {
            int ui = i*64 + lane;
            int pt = ui >> 4, ch = (ui & 15)*2;
            cgu[ui] = bf16pk(ot[pt*34 + ch], ot[pt*34 + ch + 1]);
        }
        if (lane < 16) dens[wlocal + t*16 + lane] = ot[lane*34 + 32];
    }
}

// ---- kernel 3: coarse march + pdf + importance samples + fine point gen ----
__global__ __launch_bounds__(256) void k_imp(const float* __restrict__ u, float* ws,
                                             const float* __restrict__ ro,
                                             const float* __restrict__ rd,
                                             float4* __restrict__ pts) {
    __shared__ float zl[4][48];
    __shared__ float cdfl[4][46];
    int tid = threadIdx.x;
    int wv = tid >> 6, lane = tid & 63;
    int r = blockIdx.x*4 + wv;
    const float* z   = ws + OFF_DC + (size_t)r*48;
    const float* den = ws + OFF_SC + (size_t)r*48;
    float zv = 0.f, dv = 0.f;
    if (lane < 48) { zv = z[lane]; dv = den[lane]; zl[wv][lane] = zv; }
    float zn  = __shfl_down(zv, 1);
    float dnn = __shfl_down(dv, 1);
    float alpha = 0.f, f = 1.f;
    if (lane < 47) {
        float sp = softplus_f(0.5f*(dv + dnn) - 1.f);
        alpha = 1.f - __expf(-sp*(zn - zv));
        f = 1.f - alpha + 1e-10f;
    }
    float v = f;
    for (int off = 1; off < 64; off <<= 1) { float o = __shfl_up(v, off); if (lane >= off) v *= o; }
    float T = __shfl_up(v, 1); if (lane == 0) T = 1.f;
    float w = alpha*T;
    float wn1 = __shfl_down(w, 1), wn2 = __shfl_down(w, 2);
    float pw = 0.f;
    if (lane < 45) pw = 0.5f*(fmaxf(w, wn1) + fmaxf(wn1, wn2)) + 0.01f + 1e-5f;
    float s = pw;
    for (int off = 1; off < 64; off <<= 1) { float o = __shfl_up(s, off); if (lane >= off) s += o; }
    float csum = __shfl(s, 63);
    if (lane < 45) cdfl[wv][lane+1] = s/csum;
    if (lane == 63) cdfl[wv][0] = 0.f;
    __syncthreads();
    if (lane < 48) {
        float uu = u[(size_t)r*48 + lane];
        int lo = 0, hi = 46;
        while (lo < hi) { int mid = (lo+hi)>>1; if (uu >= cdfl[wv][mid]) lo = mid+1; else hi = mid; }
        int below = max(lo-1, 0), above = min(lo, 45);
        float cb = cdfl[wv][below], ca = cdfl[wv][above];
        float zb = zl[wv][below],   za = zl[wv][above];
        float dn2 = ca - cb; if (dn2 < 1e-5f) dn2 = 1.f;
        float df_s = zb + (uu - cb)/dn2*(za - zb);
        ws[OFF_DF + (size_t)r*48 + lane] = df_s;
        float fx = fmaf(df_s, rd[r*3+0], ro[r*3+0]);
        float fy = fmaf(df_s, rd[r*3+1], ro[r*3+1]);
        float fz = fmaf(df_s, rd[r*3+2], ro[r*3+2]);
        pts[(size_t)r*48 + lane] = make_float4(fx, fy, fz, df_s);
    }
}

// ---- kernel 5: fused sort + march + color accumulation (wave per ray) ----
__global__ __launch_bounds__(256) void k_final(float* __restrict__ out, const float* __restrict__ ws,
                                               const unsigned short* __restrict__ cC,
                                               const unsigned short* __restrict__ cF)
{
    __shared__ float kd[4][96];
    __shared__ float kden[4][96];
    __shared__ float sdl[4][96];
    __shared__ float sdenl[4][96];
    __shared__ int   sidxl[4][96];
    __shared__ float warr[4][96];
    __shared__ float earr[4][96];
    int tid = threadIdx.x;
    int wv = tid >> 6, lane = tid & 63;
    int r = blockIdx.x*4 + wv;
    const float* dc = ws + OFF_DC + (size_t)r*48;
    const float* df = ws + OFF_DF + (size_t)r*48;
    const float* sc = ws + OFF_SC + (size_t)r*48;
    const float* sf = ws + OFF_SF + (size_t)r*48;
    for (int i = lane; i < 96; i += 64) {
        float d, dn;
        if (i < 48) { d = dc[i]; dn = sc[i]; }
        else        { d = df[i-48]; dn = sf[i-48]; }
        kd[wv][i] = d; kden[wv][i] = dn;
    }
    __syncthreads();
    for (int i = lane; i < 96; i += 64) {
        float d = kd[wv][i];
        int rank = 0;
        for (int j = 0; j < 96; j++) {
            float dj = kd[wv][j];
            rank += (int)((dj < d) | ((dj == d) & (j < i)));
        }
        sdl[wv][rank] = d; sdenl[wv][rank] = kden[wv][i]; sidxl[wv][rank] = i;
    }
    __syncthreads();
    int i2 = 2*lane;
    float a0=0.f, f0=1.f, a1=0.f, f1=1.f, d0=0.f, d1=0.f, d2=0.f;
    if (i2 < 95) {
        d0 = sdl[wv][i2]; d1 = sdl[wv][i2+1];
        float sp = softplus_f(0.5f*(sdenl[wv][i2] + sdenl[wv][i2+1]) - 1.f);
        a0 = 1.f - __expf(-sp*(d1 - d0)); f0 = 1.f - a0 + 1e-10f;
    }
    if (i2+1 < 95) {
        d2 = sdl[wv][i2+2];
        float sp = softplus_f(0.5f*(sdenl[wv][i2+1] + sdenl[wv][i2+2]) - 1.f);
        a1 = 1.f - __expf(-sp*(d2 - d1)); f1 = 1.f - a1 + 1e-10f;
    }
    float p = f0*f1, v = p;
    for (int off = 1; off < 64; off <<= 1) { float o = __shfl_up(v, off); if (lane >= off) v *= o; }
    float excl = __shfl_up(v, 1); if (lane == 0) excl = 1.f;
    float w0 = a0*excl, w1 = a1*excl*f0;
    if (i2   < 96) warr[wv][i2]   = w0;
    if (i2+1 < 96) warr[wv][i2+1] = w1;
    float wsm = w0 + w1;
    float dsm = w0*0.5f*(d0+d1) + w1*0.5f*(d1+d2);
    for (int off = 32; off; off >>= 1) { wsm += __shfl_xor(wsm, off); dsm += __shfl_xor(dsm, off); }
    __syncthreads();
    for (int i = lane; i < 96; i += 64) {
        float wp = (i > 0)  ? warr[wv][i-1] : 0.f;
        float wc = (i < 95) ? warr[wv][i]   : 0.f;
        earr[wv][sidxl[wv][i]] = 0.5f*(wp + wc);
    }
    __syncthreads();
    int ch = lane & 31, half = lane >> 5;
    const unsigned short* cbase = (half ? cF : cC) + ((size_t)r*48)*32 + ch;
    const float* eb = &earr[wv][half*48];
    float a = 0.f;
    for (int jj = 0; jj < 48; jj++)
        a = fmaf(eb[jj], bf2f(cbase[(size_t)jj*32]), a);
    a += __shfl_xor(a, 32);
    if (lane < 32) out[(size_t)r*34 + lane] = 2.f*a - 1.f;
    if (lane == 0) {
        float gmn = ws[OFF_MINMAX];
        float gmx = ws[OFF_MINMAX + 1];
        float depth = dsm/wsm;
        if (depth != depth) depth = __builtin_inff();
        depth = fminf(fmaxf(depth, gmn), gmx);
        out[(size_t)r*34 + 32] = depth;
        out[(size_t)r*34 + 33] = wsm;
    }
}

extern "C" void kernel_launch(void* const* d_in, const int* in_sizes, int n_in,
                              void* d_out, int out_size, void* d_ws, size_t ws_size,
                              hipStream_t stream) {
    const float* planes = (const float*)d_in[0];
    const float* ro     = (const float*)d_in[1];
    const float* rd     = (const float*)d_in[2];
    const float* noise  = (const float*)d_in[3];
    const float* u      = (const float*)d_in[4];
    const float* W1     = (const float*)d_in[5];
    const float* b1     = (const float*)d_in[6];
    const float* W2     = (const float*)d_in[7];
    const float* b2     = (const float*)d_in[8];
    float* ws  = (float*)d_ws;
    float* out = (float*)d_out;
    const unsigned short* w1e = (const unsigned short*)(ws + OFF_W1E);
    const unsigned short* w2e = (const unsigned short*)(ws + OFF_W2E);
    const uint4* stq = (const uint4*)(ws + OFF_ST);
    float4* pts = (float4*)(ws + OFF_PTS);
    unsigned short* cC = (unsigned short*)(ws + OFF_CC);
    unsigned short* cF = (unsigned short*)(ws + OFF_CF);

    hipLaunchKernelGGL(k_setup, dim3(SETUP_GRID), dim3(256), 0, stream,
                       ws, W1, W2, b2, planes, noise, ro, rd);
    hipLaunchKernelGGL(k_fused, dim3(NBLK_FUSED), dim3(256), 0, stream,
                       stq, pts, ws + OFF_POSES, b1, w1e, w2e, ws + OFF_B2E, cC, ws + OFF_SC);
    hipLaunchKernelGGL(k_imp, dim3(NRAYS/4), dim3(256), 0, stream, u, ws, ro, rd, pts);
    hipLaunchKernelGGL(k_fused, dim3(NBLK_FUSED), dim3(256), 0, stream,
                       stq, pts, ws + OFF_POSES, b1, w1e, w2e, ws + OFF_B2E, cF, ws + OFF_SF);
    hipLaunchKernelGGL(k_final, dim3(NRAYS/4), dim3(256), 0, stream, out, ws, cC, cF);
}